// Round 3
// baseline (109.508 us; speedup 1.0000x reference)
//
#include <hip/hip_runtime.h>

// Radix2ModGroup: per 8-element group, quantize to int magnitude (SF=0.05,
// |q|<=255), keep the 12 largest-exponent power-of-two terms across the
// group's 64 (element,bit) candidates (ties -> lowest element index),
// reconstruct.
//
// R7: pair-cooperative scheme — zero redistribution.
//   History: R0 32B/lane stride, 28.4us kernel; R5 64B stride, 34.7us
//   (request-rate bound: +3.2us per extra request/64B-line); R6 16B stride
//   + 32 ds_bpermute redistribution, 26us. The remaining gap to the 21.3us
//   copy floor (134MB @ 6.29TB/s) is the redistribution tax.
//   This version: each lane loads ONE float4 (16B stride = exact copy
//   pattern, 1 req/line), quantizes its own 4 elements, packs them in one
//   u32, and exchanges packed words within the lane PAIR via a single
//   __shfl_xor(,1) — a group of 8 elements spans exactly lanes (2j, 2j+1).
//   Both lanes duplicate the cheap selection (transpose + rank-select) on
//   the identical u64, then each extracts its own 4 kept bytes and stores
//   its own float4. 32 bpermute + 16 cndmask/thread -> 1 swizzle/thread.
//
// Retained from previous rounds (do not revert):
//  - 16B lane stride for ALL global access (1 request/line; 32B costs
//    +3.2us, 64B +6.4us).
//  - fabs-first quantization: round(|x|/SF) == |round(x/SF)| (RTNE and the
//    Markstein sequence are sign-symmetric); clamp is one v_min_f32.
//    Validated absmax 0 in R5/R6.
//  - branchless selection: 8x8 bit-transpose puts candidate (exponent e,
//    element i) at bit 8e+(7-i) — strict priority (exponent major, low
//    element index minor), so top-12 terms == top-12 set bits
//    (branchless rank-select).
//  - x/0.05f bit-exact via Markstein: RN(1/0.05f) == 20.0f exactly;
//    q0=m*20; r=fma(-0.05,q0,m); q=fma(r,20,q0) is the correctly rounded
//    IEEE quotient for all normal-range inputs. Validated absmax 0.
//  - nontemporal hints measured SLOWER on gfx950; do not re-add.
//  - do NOT widen per-thread work (R5 regression).

constexpr float SF = 0.05f;
constexpr float RCP = 20.0f;   // RN(1 / 0.05f) == 20.0f exactly
constexpr int NUM_EXPS = 12;

__device__ __forceinline__ unsigned long long transpose8x8(unsigned long long x) {
  // bit(8r+c) <-> bit(8c+r)  (Hacker's Delight 8x8 bit-matrix transpose)
  unsigned long long t;
  t = (x ^ (x >> 7)) & 0x00AA00AA00AA00AAull; x ^= t ^ (t << 7);
  t = (x ^ (x >> 14)) & 0x0000CCCC0000CCCCull; x ^= t ^ (t << 14);
  t = (x ^ (x >> 28)) & 0x00000000F0F0F0F0ull; x ^= t ^ (t << 28);
  return x;
}

__global__ __launch_bounds__(256) void radix2_mod_group_kernel(
    const float4* __restrict__ xv, float4* __restrict__ ov) {
  int t = blockIdx.x * blockDim.x + threadIdx.x;  // one float4 per thread
  int p = t & 1;  // pair parity: 0 -> group elements 0-3, 1 -> elements 4-7

  // Exact copy pattern: 16B lane stride, 1 request per 64B line.
  float4 a = xv[t];
  float v[4] = {a.x, a.y, a.z, a.w};

  // Quantize |v|; pack own 4 magnitudes into u32, byte (3-k) = mag of
  // local element k (element-priority order within the half-group).
  unsigned P = 0u;
#pragma unroll
  for (int k = 0; k < 4; ++k) {
    float m  = __builtin_fabsf(v[k]);          // free input modifier
    float q0 = m * RCP;
    float r0 = __builtin_fmaf(-SF, q0, m);
    float q  = __builtin_fmaf(r0, RCP, q0);    // == |v[k]| / 0.05f, exact
    float r  = fminf(rintf(q), 255.0f);        // RTNE == jnp.round; q >= 0
    unsigned mi = (unsigned)r;                 // exact, in [0,255]
    P |= mi << (24 - 8 * k);
  }

  // Single 32-bit exchange within the lane pair (group j = lanes 2j,2j+1).
  unsigned Q = (unsigned)__shfl_xor((int)P, 1);

  // Both lanes build the identical group word:
  // M byte (7-i) = mag of group element i  (even lane's elems are 0-3).
  unsigned hi = p ? Q : P;
  unsigned lo = p ? P : Q;
  unsigned long long M = ((unsigned long long)hi << 32) | lo;

  // w bit (8e + (7-i)) = bit e of mag_i. Position = selection priority.
  unsigned long long w = transpose8x8(M);

  // Drop the jj = max(P-12, 0) lowest-priority set bits.
  int Pc = __popcll(w);
  int jj = Pc > NUM_EXPS ? Pc - NUM_EXPS : 0;

  // Branchless rank-select: pos = index of the (jj+1)-th set bit from LSB.
  unsigned long long xx = w;
  int pos = 0;
  int c;
  c = __popcll(xx & 0xffffffffull);
  { int s = (jj >= c); pos += s << 5; jj -= s ? c : 0; xx = s ? (xx >> 32) : xx; }
  c = __popc((unsigned)xx & 0xffffu);
  { int s = (jj >= c); pos += s << 4; jj -= s ? c : 0; xx = s ? (xx >> 16) : xx; }
  c = __popc((unsigned)xx & 0xffu);
  { int s = (jj >= c); pos += s << 3; jj -= s ? c : 0; xx = s ? (xx >> 8) : xx; }
  c = __popc((unsigned)xx & 0xfu);
  { int s = (jj >= c); pos += s << 2; jj -= s ? c : 0; xx = s ? (xx >> 4) : xx; }
  c = __popc((unsigned)xx & 0x3u);
  { int s = (jj >= c); pos += s << 1; jj -= s ? c : 0; xx = s ? (xx >> 2) : xx; }
  c = (int)((unsigned)xx & 1u);
  { int s = (jj >= c); pos += s; }

  unsigned long long keep = w & (~0ull << pos);

  // Transpose back: byte (7-i) of Kt = kept magnitude of element i.
  unsigned long long Kt = transpose8x8(keep);

  // Extract own half: even lane -> bytes 7..4 (elements 0-3),
  // odd lane -> bytes 3..0 (elements 4-7). Byte (3-k) of 'my' = local k.
  unsigned my = (unsigned)(Kt >> (p ? 0 : 32));

  float o[4];
#pragma unroll
  for (int k = 0; k < 4; ++k) {
    unsigned mi = (my >> (24 - 8 * k)) & 0xffu;
    // sign of q == sign of x whenever mag != 0; mag==0 -> +/-0 == 0.
    o[k] = copysignf((float)mi * SF, v[k]);
  }

  // Exact copy pattern out: 16B lane stride.
  ov[t] = make_float4(o[0], o[1], o[2], o[3]);
}

extern "C" void kernel_launch(void* const* d_in, const int* in_sizes, int n_in,
                              void* d_out, int out_size, void* d_ws, size_t ws_size,
                              hipStream_t stream) {
  const float* x = (const float*)d_in[0];
  float* out = (float*)d_out;
  int n = in_sizes[0];            // elements: 16,777,216 for 4096x4096
  int nthreads = n / 4;           // one float4 (half-group) per thread
  int block = 256;
  int grid = nthreads / block;    // 16384; divides exactly, no tail guard
  radix2_mod_group_kernel<<<grid, block, 0, stream>>>(
      (const float4*)x, (float4*)out);
}

// Round 4
// 109.260 us; speedup vs baseline: 1.0023x; 1.0023x over previous
//
#include <hip/hip_runtime.h>

// Radix2ModGroup: per 8-element group, quantize to int magnitude (SF=0.05,
// |q|<=255), keep the 12 largest-exponent power-of-two terms across the
// group's 64 (element,bit) candidates (ties -> lowest element index),
// reconstruct.
//
// R8: pair-cooperative (R7) + 2 independent COALESCED chunks per thread.
//   History: R0 32B/lane stride 28.4us; R5 64B stride 34.7us (request-rate:
//   +3.2us per extra req/64B-line — the regression was the STRIDE, not the
//   widening); R6 16B stride + bpermute redistribution 26us; R7 removed the
//   redistribution entirely (1 shfl_xor) — NEUTRAL at ~26.5us. So neither
//   cross-lane ops nor VALU count is the remaining bottleneck; what's left
//   vs the 21.3us copy floor (134MB @ 6.29TB/s) is per-thread MLP/ILP:
//   1 load -> ~50-op serial chain (transpose/rank-select) -> 1 store.
//   This version: each thread processes float4s t and t+NV/2. Each access
//   keeps the exact 16B-lane-stride copy pattern (1 req/line); both loads
//   issue before any compute (2x outstanding loads/wave) and the two
//   selection chains are independent (2x ILP). NV/2 is even, so pair
//   parity and the shfl partner are preserved for the second chunk.
//
// Retained (do not revert):
//  - 16B lane stride for EVERY global access (32B costs +3.2us, 64B +6.4us).
//  - pair-cooperative selection: group j = lanes (2j,2j+1); one
//    __shfl_xor(,1) exchanges packed magnitudes; both lanes duplicate the
//    cheap selection; each extracts its own 4 bytes. Validated absmax 0.
//  - fabs-first quantization: round(|x|/SF) == |round(x/SF)| (RTNE and the
//    Markstein sequence are sign-symmetric); clamp is one v_min_f32.
//  - branchless selection: 8x8 bit-transpose puts candidate (exponent e,
//    element i) at bit 8e+(7-i) — strict priority, so top-12 terms ==
//    top-12 set bits (branchless rank-select). Validated absmax 0.
//  - x/0.05f bit-exact via Markstein: RN(1/0.05f)==20.0f; q0=m*20;
//    r=fma(-0.05,q0,m); q=fma(r,20,q0). Validated absmax 0.
//  - nontemporal hints measured SLOWER on gfx950; do not re-add.

constexpr float SF = 0.05f;
constexpr float RCP = 20.0f;   // RN(1 / 0.05f) == 20.0f exactly
constexpr int NUM_EXPS = 12;

__device__ __forceinline__ unsigned long long transpose8x8(unsigned long long x) {
  // bit(8r+c) <-> bit(8c+r)  (Hacker's Delight 8x8 bit-matrix transpose)
  unsigned long long t;
  t = (x ^ (x >> 7)) & 0x00AA00AA00AA00AAull; x ^= t ^ (t << 7);
  t = (x ^ (x >> 14)) & 0x0000CCCC0000CCCCull; x ^= t ^ (t << 14);
  t = (x ^ (x >> 28)) & 0x00000000F0F0F0F0ull; x ^= t ^ (t << 28);
  return x;
}

// Quantize own 4 elements -> packed u32, byte (3-k) = magnitude of local k.
__device__ __forceinline__ unsigned quant4(const float v[4]) {
  unsigned P = 0u;
#pragma unroll
  for (int k = 0; k < 4; ++k) {
    float m  = __builtin_fabsf(v[k]);          // free input modifier
    float q0 = m * RCP;
    float r0 = __builtin_fmaf(-SF, q0, m);
    float q  = __builtin_fmaf(r0, RCP, q0);    // == |v[k]| / 0.05f, exact
    float r  = fminf(rintf(q), 255.0f);        // RTNE == jnp.round; q >= 0
    P |= ((unsigned)r) << (24 - 8 * k);
  }
  return P;
}

// Given own packed word P and partner's Q, parity p (0: elems 0-3, 1: 4-7),
// run the group selection and return own 4 kept magnitudes (packed u32).
__device__ __forceinline__ unsigned select_own(unsigned P, unsigned Q, int p) {
  unsigned hi = p ? Q : P;
  unsigned lo = p ? P : Q;
  unsigned long long M = ((unsigned long long)hi << 32) | lo;

  // w bit (8e + (7-i)) = bit e of mag_i. Position = selection priority.
  unsigned long long w = transpose8x8(M);

  // Drop the jj = max(pop-12, 0) lowest-priority set bits.
  int Pc = __popcll(w);
  int jj = Pc > NUM_EXPS ? Pc - NUM_EXPS : 0;

  // Branchless rank-select: pos = index of the (jj+1)-th set bit from LSB.
  unsigned long long xx = w;
  int pos = 0;
  int c;
  c = __popcll(xx & 0xffffffffull);
  { int s = (jj >= c); pos += s << 5; jj -= s ? c : 0; xx = s ? (xx >> 32) : xx; }
  c = __popc((unsigned)xx & 0xffffu);
  { int s = (jj >= c); pos += s << 4; jj -= s ? c : 0; xx = s ? (xx >> 16) : xx; }
  c = __popc((unsigned)xx & 0xffu);
  { int s = (jj >= c); pos += s << 3; jj -= s ? c : 0; xx = s ? (xx >> 8) : xx; }
  c = __popc((unsigned)xx & 0xfu);
  { int s = (jj >= c); pos += s << 2; jj -= s ? c : 0; xx = s ? (xx >> 4) : xx; }
  c = __popc((unsigned)xx & 0x3u);
  { int s = (jj >= c); pos += s << 1; jj -= s ? c : 0; xx = s ? (xx >> 2) : xx; }
  c = (int)((unsigned)xx & 1u);
  { int s = (jj >= c); pos += s; }

  unsigned long long keep = w & (~0ull << pos);

  // Transpose back: byte (7-i) of Kt = kept magnitude of element i.
  unsigned long long Kt = transpose8x8(keep);

  // Own half: even lane -> bytes 7..4, odd lane -> bytes 3..0.
  return (unsigned)(Kt >> (p ? 0 : 32));
}

__global__ __launch_bounds__(256) void radix2_mod_group_kernel(
    const float4* __restrict__ xv, float4* __restrict__ ov, int half) {
  int t = blockIdx.x * blockDim.x + threadIdx.x;
  int p = t & 1;  // pair parity; (t+half)&1 == p since half is even

  // Two chunks, EACH at the exact 16B-lane-stride copy pattern.
  // Both loads issue before any compute (2x outstanding per wave).
  float4 a0 = xv[t];
  float4 a1 = xv[t + half];

  float v0[4] = {a0.x, a0.y, a0.z, a0.w};
  float v1[4] = {a1.x, a1.y, a1.z, a1.w};

  unsigned P0 = quant4(v0);
  unsigned P1 = quant4(v1);

  // One exchange each within the lane pair (group j = lanes 2j,2j+1).
  unsigned Q0 = (unsigned)__shfl_xor((int)P0, 1);
  unsigned Q1 = (unsigned)__shfl_xor((int)P1, 1);

  // Two independent selection chains (2x ILP on the serial part).
  unsigned my0 = select_own(P0, Q0, p);
  unsigned my1 = select_own(P1, Q1, p);

  float4 o0, o1;
  {
    float* o = &o0.x;
#pragma unroll
    for (int k = 0; k < 4; ++k) {
      unsigned mi = (my0 >> (24 - 8 * k)) & 0xffu;
      o[k] = copysignf((float)mi * SF, v0[k]);  // mag==0 -> +/-0 == 0
    }
  }
  {
    float* o = &o1.x;
#pragma unroll
    for (int k = 0; k < 4; ++k) {
      unsigned mi = (my1 >> (24 - 8 * k)) & 0xffu;
      o[k] = copysignf((float)mi * SF, v1[k]);
    }
  }

  ov[t] = o0;
  ov[t + half] = o1;
}

extern "C" void kernel_launch(void* const* d_in, const int* in_sizes, int n_in,
                              void* d_out, int out_size, void* d_ws, size_t ws_size,
                              hipStream_t stream) {
  const float* x = (const float*)d_in[0];
  float* out = (float*)d_out;
  int n = in_sizes[0];            // elements: 16,777,216 for 4096x4096
  int nv = n / 4;                 // float4 count: 4,194,304
  int half = nv / 2;              // 2,097,152 (even -> parity preserved)
  int block = 256;
  int grid = half / block;        // 8192; divides exactly, no tail guard
  radix2_mod_group_kernel<<<grid, block, 0, stream>>>(
      (const float4*)x, (float4*)out, half);
}